// Round 3
// baseline (203.569 us; speedup 1.0000x reference)
//
#include <hip/hip_runtime.h>
#include <hip/hip_bf16.h>
#include <stdint.h>

typedef unsigned short u16;
typedef __bf16 bf16x8 __attribute__((ext_vector_type(8)));
typedef float f32x4 __attribute__((ext_vector_type(4)));

#define MFMA_16x16x32(a, b, c) __builtin_amdgcn_mfma_f32_16x16x32_bf16((a), (b), (c), 0, 0, 0)

__device__ __forceinline__ u16 f2b(float f) {
  __bf16 h = (__bf16)f;
  return __builtin_bit_cast(u16, h);
}

// Output store: bf16 (u16 container) or fp32, chosen by pointer type.
__device__ __forceinline__ void store_c(u16* C, size_t idx, float v) { C[idx] = f2b(v); }
__device__ __forceinline__ void store_c(float* C, size_t idx, float v) { C[idx] = v; }

// async global->LDS, 16B per lane. LDS dest is wave-uniform base; HW adds lane*16B.
__device__ __forceinline__ void gload16(const void* g, void* l) {
  __builtin_amdgcn_global_load_lds(
      (const __attribute__((address_space(1))) unsigned int*)(uintptr_t)(g),
      (__attribute__((address_space(3))) unsigned int*)(uintptr_t)(l),
      16, 0, 0);
}

// Load an 8-wide k-slot MFMA fragment from LDS tile [128][32] (row-major, ld=32).
__device__ __forceinline__ bf16x8 load_frag(const u16* Ls, int off) {
  return *(const bf16x8*)(Ls + off);  // already bf16
}
__device__ __forceinline__ bf16x8 load_frag(const float* Ls, int off) {
  f32x4 lo = *(const f32x4*)(Ls + off);
  f32x4 hi = *(const f32x4*)(Ls + off + 4);
  bf16x8 r;
#pragma unroll
  for (int e = 0; e < 4; e++) {
    r[e] = (__bf16)lo[e];
    r[e + 4] = (__bf16)hi[e];
  }
  return r;
}

// Stage one 128x32 tile (element type T) global -> LDS via global_load_lds.
// Flat layout: idx = r*32 + c. Each call: one wave, 64 lanes x 16B.
template <typename T>
__device__ __forceinline__ void stage_tile(const T* __restrict__ G, int ldg, int tr, int k0,
                                           T* Ls, int wave, int lane) {
  constexpr int EPL = 16 / sizeof(T);             // elements per lane per call
  constexpr int PCE = 64 * EPL;                   // elements per call
  constexpr int CALLS = (128 * 32) / (4 * PCE);   // calls per wave
#pragma unroll
  for (int ci = 0; ci < CALLS; ci++) {
    const int base = (wave * CALLS + ci) * PCE;   // wave-uniform
    const int idx0 = base + lane * EPL;
    const int r = idx0 >> 5;
    const int c = idx0 & 31;
    gload16(G + (size_t)(tr + r) * ldg + k0 + c, Ls + base);
  }
}

// C[M,N] = A[M,K] @ B[N,K]^T (+ bias); A/B storage fp32 or bf16(u16); C bf16 or fp32.
// fp32 accum. 128x128 tile, BK=32, 4 waves, each wave a 64x64 subtile (4x4 frags).
template <typename TA, typename TB, typename TC, bool BIAS>
__global__ __launch_bounds__(256) void gemm_bt(const TA* __restrict__ A,
                                               const TB* __restrict__ B,
                                               const float* __restrict__ bias,
                                               TC* __restrict__ C,
                                               int M, int N, int K) {
  __shared__ TA As[128 * 32];
  __shared__ TB Bs[128 * 32];
  const int tid = threadIdx.x;
  const int lane = tid & 63;
  const int wave = tid >> 6;
  const int l15 = lane & 15;
  const int g = lane >> 4;
  const int g8 = g * 8;
  const int tiles_n = N >> 7;
  const int tm = (int)(blockIdx.x / tiles_n) << 7;
  const int tn = (int)(blockIdx.x % tiles_n) << 7;
  const int wm = (wave >> 1) << 6;
  const int wn = (wave & 1) << 6;

  f32x4 acc[4][4] = {};

  for (int k0 = 0; k0 < K; k0 += 32) {
    __syncthreads();
    stage_tile<TA>(A, K, tm, k0, As, wave, lane);
    stage_tile<TB>(B, K, tn, k0, Bs, wave, lane);
    __syncthreads();
    bf16x8 af[4], bfr[4];
#pragma unroll
    for (int i = 0; i < 4; i++) {
      af[i] = load_frag(As, (wm + i * 16 + l15) * 32 + g8);
      bfr[i] = load_frag(Bs, (wn + i * 16 + l15) * 32 + g8);
    }
#pragma unroll
    for (int mi = 0; mi < 4; mi++)
#pragma unroll
      for (int nj = 0; nj < 4; nj++)
        acc[mi][nj] = MFMA_16x16x32(af[mi], bfr[nj], acc[mi][nj]);
  }

  float bv[4];
#pragma unroll
  for (int nj = 0; nj < 4; nj++)
    bv[nj] = BIAS ? bias[tn + wn + nj * 16 + l15] : 0.0f;

#pragma unroll
  for (int mi = 0; mi < 4; mi++) {
#pragma unroll
    for (int nj = 0; nj < 4; nj++) {
      const int row = tm + wm + mi * 16 + g * 4;
      const int col = tn + wn + nj * 16 + l15;
#pragma unroll
      for (int r = 0; r < 4; r++)
        store_c(C, (size_t)(row + r) * N + col, acc[mi][nj][r] + bv[nj]);
    }
  }
}

// Flash attention over bf16 qkv buffer (4096 x 3072): one block per (b,h,64-q-row tile).
// 4 waves x 16 q-rows; wave-parallel online softmax; V transposed in LDS; P via LDS.
__global__ __launch_bounds__(256) void attn(const u16* __restrict__ qkv,
                                            u16* __restrict__ attout) {
  __shared__ u16 Vt[64 * 64];  // [hd][key]
  __shared__ u16 Pl[64 * 64];  // [q][key]
  const int tid = threadIdx.x;
  const int lane = tid & 63;
  const int wave = tid >> 6;
  const int l15 = lane & 15;
  const int g = lane >> 4;
  const int g8 = g * 8;

  const int bh = blockIdx.x >> 4;
  const int qt = blockIdx.x & 15;
  const int b = bh >> 4;
  const int h = bh & 15;
  const size_t rowbase = (size_t)b * 1024;
  const int qcol = h * 64;

  bf16x8 qf[2];
  {
    const size_t qrow = rowbase + qt * 64 + wave * 16 + l15;
#pragma unroll
    for (int ks = 0; ks < 2; ks++)
      qf[ks] = *(const bf16x8*)&qkv[qrow * 3072 + qcol + ks * 32 + g8];
  }

  f32x4 o[4] = {};
  float m_r[4], l_r[4];
#pragma unroll
  for (int r = 0; r < 4; r++) { m_r[r] = -1e30f; l_r[r] = 0.0f; }

  for (int kt = 0; kt < 16; kt++) {
    __syncthreads();  // prev iter's Vt reads done before overwrite
#pragma unroll
    for (int it = 0; it < 2; it++) {
      int idx = it * 256 + tid;
      int key = idx >> 3;
      int hc = (idx & 7) << 3;
      bf16x8 v = *(const bf16x8*)&qkv[(rowbase + kt * 64 + key) * 3072 + 2048 + qcol + hc];
      const u16* vu = (const u16*)&v;
#pragma unroll
      for (int e = 0; e < 8; e++) Vt[(hc + e) * 64 + key] = vu[e];
    }
    __syncthreads();

    // S = Q K^T for this 64-key tile; per wave 16x64 in 4 frags
    f32x4 s[4] = {};
#pragma unroll
    for (int nj = 0; nj < 4; nj++) {
      const size_t krow = rowbase + kt * 64 + nj * 16 + l15;
#pragma unroll
      for (int ks = 0; ks < 2; ks++) {
        bf16x8 kf = *(const bf16x8*)&qkv[krow * 3072 + 1024 + qcol + ks * 32 + g8];
        s[nj] = MFMA_16x16x32(qf[ks], kf, s[nj]);
      }
    }
#pragma unroll
    for (int nj = 0; nj < 4; nj++)
#pragma unroll
      for (int r = 0; r < 4; r++) s[nj][r] *= 0.125f;

    // online softmax (row = g*4 + r; reduce across the 16 lanes of group g)
    float pvv[4][4];
#pragma unroll
    for (int r = 0; r < 4; r++) {
      float mx = fmaxf(fmaxf(s[0][r], s[1][r]), fmaxf(s[2][r], s[3][r]));
#pragma unroll
      for (int d = 1; d < 16; d <<= 1) mx = fmaxf(mx, __shfl_xor(mx, d, 64));
      float nm = fmaxf(m_r[r], mx);
      float alpha = __expf(m_r[r] - nm);
      m_r[r] = nm;
      float rs = 0.0f;
#pragma unroll
      for (int nj = 0; nj < 4; nj++) {
        float p = __expf(s[nj][r] - nm);
        pvv[nj][r] = p;
        rs += p;
      }
#pragma unroll
      for (int d = 1; d < 16; d <<= 1) rs += __shfl_xor(rs, d, 64);
      l_r[r] = l_r[r] * alpha + rs;
#pragma unroll
      for (int nj = 0; nj < 4; nj++) o[nj][r] *= alpha;
    }

    // P -> LDS (bf16); wave-private 16 rows, no cross-wave hazard
#pragma unroll
    for (int nj = 0; nj < 4; nj++)
#pragma unroll
      for (int r = 0; r < 4; r++)
        Pl[(wave * 16 + g * 4 + r) * 64 + nj * 16 + l15] = f2b(pvv[nj][r]);

    bf16x8 pf[2];
#pragma unroll
    for (int ks = 0; ks < 2; ks++)
      pf[ks] = *(const bf16x8*)&Pl[(wave * 16 + l15) * 64 + ks * 32 + g8];
#pragma unroll
    for (int nj = 0; nj < 4; nj++)
#pragma unroll
      for (int ks = 0; ks < 2; ks++) {
        bf16x8 vf = *(const bf16x8*)&Vt[(nj * 16 + l15) * 64 + ks * 32 + g8];
        o[nj] = MFMA_16x16x32(pf[ks], vf, o[nj]);
      }
  }

  float inv[4];
#pragma unroll
  for (int r = 0; r < 4; r++) inv[r] = 1.0f / l_r[r];
#pragma unroll
  for (int nj = 0; nj < 4; nj++)
#pragma unroll
    for (int r = 0; r < 4; r++)
      attout[(rowbase + qt * 64 + wave * 16 + g * 4 + r) * 1024 + qcol + nj * 16 + l15] =
          f2b(o[nj][r] * inv[r]);
}

extern "C" void kernel_launch(void* const* d_in, const int* in_sizes, int n_in,
                              void* d_out, int out_size, void* d_ws, size_t ws_size,
                              hipStream_t stream) {
  const float* x = (const float*)d_in[0];      // (4,1024,1024) fp32
  const float* w_qkv = (const float*)d_in[1];  // (3072,1024) fp32
  const float* w_out = (const float*)d_in[2];  // (1024,1024) fp32
  const float* b_out = (const float*)d_in[3];  // (1024,) fp32
  float* out = (float*)d_out;                  // (4,1024,1024) fp32

  u16* qkv = (u16*)d_ws;                    // 4096*3072 bf16 = 25.2 MB
  u16* attout = qkv + (size_t)4096 * 3072;  // 4096*1024 bf16 = 8.4 MB

  // 1) qkv = x @ w_qkv^T   (M=4096, N=3072, K=1024), fp32 in, bf16 out
  gemm_bt<float, float, u16, false><<<dim3(32 * 24), dim3(256), 0, stream>>>(
      x, w_qkv, nullptr, qkv, 4096, 3072, 1024);
  // 2) attention per (b,h), flash-style, bf16
  attn<<<dim3(1024), dim3(256), 0, stream>>>(qkv, attout);
  // 3) out = attout @ w_out^T + b_out  (M=4096, N=1024, K=1024), fp32 out
  gemm_bt<u16, float, float, true><<<dim3(32 * 8), dim3(256), 0, stream>>>(
      attout, w_out, b_out, out, 4096, 1024, 1024);
}